// Round 8
// baseline (251.321 us; speedup 1.0000x reference)
//
#include <hip/hip_runtime.h>
#include <math.h>

// VQ-VAE forward. inputs [16,256,64,64] f32 NCHW, codebook [1024,256] f32.
// N = 65536 points, D = 256, K = 1024.
// d_out f32: z_out [16,256,64,64] | loss | perplexity | idx [65536,1]
#define NPTS   65536
#define DDIM   256
#define KCODES 1024
#define HWSZ   4096
#define ZELEMS 16777216
#define CHW    1048576

// bf16-split GEMM, 3-product contraction 768 = [xhi|xhi|xlo].[whi|wlo|whi]
// (lo.lo term dropped: |err| ~1e-4 << argmin gaps O(10)).
// Fragment-ordered tiles; BK=32, 4 LDS buffers, prefetch distance 3.
// Per-tile single region: {AH reads | next-tile RD1 | stage | 32 MFMA} ->
// vmcnt(4) -> barrier. Ping-pong RD1 frag sets; no register spills.
// X layout: [mt 256][chunk 16][rhalf 2][ms 8][lane 64][8] bf16 (64 MiB, z_out scratch)
// W layout: [ct 4][chunk 16][chalf 2][ms 8][lane 64][8] bf16 (1 MiB, ws)
// ws: counts u32[1K] @0 | ww f32[1K] @4096 | partials @8192 | Ws @16384 | pbest u64[4][64K] @1064960

typedef __attribute__((ext_vector_type(8))) short s16x8;
typedef __attribute__((ext_vector_type(4))) float f32x4;

#define AS1 __attribute__((address_space(1)))
#define AS3 __attribute__((address_space(3)))

__device__ __forceinline__ void bf16split(float x, unsigned short& h, unsigned short& l) {
    unsigned u  = __float_as_uint(x);
    unsigned hu = (u + 0x8000u) & 0xFFFF0000u;
    h = (unsigned short)(hu >> 16);
    float r = x - __uint_as_float(hu);
    l = (unsigned short)((__float_as_uint(r) + 0x8000u) >> 16);
}

// ------------------------------------------- conv_w: codebook -> tiles + ||w||^2
__global__ __launch_bounds__(256) void conv_w(const float* __restrict__ cb,
                                              unsigned short* __restrict__ Ws,
                                              float* __restrict__ ww) {
    int gid  = blockIdx.x * 256 + threadIdx.x;           // 0..8191
    int code = gid >> 3, o32 = gid & 7;
    int ct = code >> 8, r256 = code & 255, rh = r256 >> 7, rr = r256 & 127;
    unsigned short hi[32], lo[32];
    float ss = 0.f;
#pragma unroll
    for (int j4 = 0; j4 < 8; ++j4) {
        float4 v = *(const float4*)(cb + (size_t)code * DDIM + o32 * 32 + j4 * 4);
        ss += v.x * v.x + v.y * v.y + v.z * v.z + v.w * v.w;
        bf16split(v.x, hi[j4*4+0], lo[j4*4+0]);
        bf16split(v.y, hi[j4*4+1], lo[j4*4+1]);
        bf16split(v.z, hi[j4*4+2], lo[j4*4+2]);
        bf16split(v.w, hi[j4*4+3], lo[j4*4+3]);
    }
    ss += __shfl_down(ss, 4, 8);
    ss += __shfl_down(ss, 2, 8);
    ss += __shfl_down(ss, 1, 8);
    if (o32 == 0) ww[code] = ss;
    size_t bh = (size_t)ct * 131072 + (size_t)o32       * 8192 + rh * 4096 + (rr >> 4) * 512;
    size_t bl = (size_t)ct * 131072 + (size_t)(o32 + 8) * 8192 + rh * 4096 + (rr >> 4) * 512;
#pragma unroll
    for (int oct = 0; oct < 4; ++oct) {
        size_t fo = (size_t)((rr & 15) + 16 * oct) * 8;
        *(s16x8*)(Ws + bh + fo) = *(const s16x8*)&hi[oct * 8];
        *(s16x8*)(Ws + bl + fo) = *(const s16x8*)&lo[oct * 8];
    }
}

// --------------------------------- conv_x: NCHW f32 -> fragment-ordered bf16
__global__ __launch_bounds__(256) void conv_x(const float* __restrict__ in,
                                              unsigned short* __restrict__ Xs) {
    __shared__ float xt[32 * 128];                       // 16 KB
    const int tid = threadIdx.x;
    const int rg = blockIdx.x >> 3, dc = blockIdx.x & 7;
    const int mt = rg >> 1, rhalf = rg & 1;
    const int b = (rg * 128) >> 12, hw0 = (rg * 128) & 4095;
    const float* src = in + (size_t)b * CHW + (size_t)(dc * 32) * HWSZ + hw0;
#pragma unroll
    for (int r = 0; r < 16; ++r) {
        int e = r * 256 + tid, dd = e >> 7, i = e & 127;
        xt[dd * 128 + i] = src[(size_t)dd * HWSZ + i];
    }
    __syncthreads();
#pragma unroll
    for (int hl = 0; hl < 2; ++hl) {
        int g = hl * 256 + tid;
        int row = g >> 2, o = g & 3;
        unsigned short hi[8], lo[8];
#pragma unroll
        for (int j = 0; j < 8; ++j)
            bf16split(xt[(o * 8 + j) * 128 + row], hi[j], lo[j]);
        size_t fo = rhalf * 4096 + (size_t)(row >> 4) * 512 + (size_t)((row & 15) + 16 * o) * 8;
        size_t bh = (size_t)mt * 131072 + (size_t)dc       * 8192 + fo;
        size_t bl = (size_t)mt * 131072 + (size_t)(dc + 8) * 8192 + fo;
        *(s16x8*)(Xs + bh) = *(const s16x8*)hi;
        *(s16x8*)(Xs + bl) = *(const s16x8*)lo;
    }
}

// --------------------------------------- gemm_argmin: pipelined MFMA + argmin
// 1024 blocks x 512 threads (8 waves 2Mx4N; wave tile 128x64). BK=32, 24 tiles.
// XCD swizzle: 4 nt-blocks of one mb run concurrently on one XCD (share X in L2).
__global__ __launch_bounds__(512) void gemm_argmin(
        const unsigned short* __restrict__ Xs, const unsigned short* __restrict__ Ws,
        const float* __restrict__ ww, unsigned long long* __restrict__ pbest) {
    __shared__ unsigned short lds[65536];                // 128 KB = 4 bufs x 16384 shorts
    const int tid = threadIdx.x, lane = tid & 63, w = tid >> 6;
    const int wm = w >> 2, wn = w & 3;
    const int col = lane & 15, q = lane >> 4;
    const int bid = blockIdx.x;
    const int xcd = bid & 7, slot = bid >> 3;
    const int nt = slot & 3, mb = (slot >> 2) * 8 + xcd;

    const unsigned short* XsB = Xs + (size_t)mb * 131072;
    const unsigned short* WsB = Ws + (size_t)nt * 131072;

    f32x4 acc[8][4] = {};
    s16x8 AL[2][4], B[2][4], AH[4];                      // ping-pong RD1 sets + AH

    const int aoff = wm * 4096 + lane * 8;
    const int boff = 8192 + (wn >> 1) * 4096 + (wn & 1) * 2048 + lane * 8;

    auto SA = [&](int g, int h) {
        const int kA = (g & 7) | ((g >> 4) << 3);        // xhi,xhi,xlo
        const unsigned short* src = XsB + kA * 8192 + h * 4096 + tid * 8;
        __builtin_amdgcn_global_load_lds(
            (const AS1 unsigned*)src,
            (AS3 unsigned*)&lds[(g & 3) * 16384 + h * 4096 + w * 512], 16, 0, 0);
    };
    auto SB = [&](int g, int h) {
        const int kW = (g & 7) | (((g >> 3) & 1) << 3);  // whi,wlo,whi
        const unsigned short* src = WsB + kW * 8192 + h * 4096 + tid * 8;
        __builtin_amdgcn_global_load_lds(
            (const AS1 unsigned*)src,
            (AS3 unsigned*)&lds[(g & 3) * 16384 + 8192 + h * 4096 + w * 512], 16, 0, 0);
    };
#define GATE4 asm volatile("s_waitcnt vmcnt(4)" ::: "memory")
#define GATE0 asm volatile("s_waitcnt vmcnt(0)" ::: "memory")
#define BAR   do { __builtin_amdgcn_s_barrier(); __builtin_amdgcn_sched_barrier(0); } while (0)

    // prologue: stage tiles 0,1,2 -> bufs 0,1,2; gate bufs 0,1; RD1(0) -> set 0
    SA(0, 0); SA(0, 1); SB(0, 0); SB(0, 1);
    SA(1, 0); SA(1, 1); SB(1, 0); SB(1, 1);
    SA(2, 0); SA(2, 1); SB(2, 0); SB(2, 1);
    GATE4;
    BAR;
#pragma unroll
    for (int nf = 0; nf < 4; ++nf) B[0][nf]  = *(const s16x8*)&lds[boff + nf * 512];
#pragma unroll
    for (int mf = 0; mf < 4; ++mf) AL[0][mf] = *(const s16x8*)&lds[aoff + mf * 512];

#pragma unroll
    for (int t = 0; t < 24; ++t) {
        const int p = t & 1, pn = p ^ 1;
        const int bb  = (t & 3) * 16384;
        const int bbn = ((t + 1) & 3) * 16384;
        // AH: a4..a7 of tile t (buf resident since end of tile t-2)
#pragma unroll
        for (int mf = 0; mf < 4; ++mf)
            AH[mf] = *(const s16x8*)&lds[bb + aoff + (4 + mf) * 512];
        // RD1(t+1): next tile's B and a0..a3 (buf t+1 resident per gate at t-1)
        if (t < 23) {
#pragma unroll
            for (int nf = 0; nf < 4; ++nf) B[pn][nf]  = *(const s16x8*)&lds[bbn + boff + nf * 512];
#pragma unroll
            for (int mf = 0; mf < 4; ++mf) AL[pn][mf] = *(const s16x8*)&lds[bbn + aoff + mf * 512];
        }
        if (t < 21) { SA(t + 3, 0); SA(t + 3, 1); SB(t + 3, 0); SB(t + 3, 1); }
        __builtin_amdgcn_s_setprio(1);
#pragma unroll
        for (int mf = 0; mf < 4; ++mf)
#pragma unroll
            for (int nf = 0; nf < 4; ++nf)
                acc[mf][nf] = __builtin_amdgcn_mfma_f32_16x16x32_bf16(AL[p][mf], B[p][nf], acc[mf][nf], 0, 0, 0);
#pragma unroll
        for (int mf = 0; mf < 4; ++mf)
#pragma unroll
            for (int nf = 0; nf < 4; ++nf)
                acc[mf + 4][nf] = __builtin_amdgcn_mfma_f32_16x16x32_bf16(AH[mf], B[p][nf], acc[mf + 4][nf], 0, 0, 0);
        __builtin_amdgcn_s_setprio(0);
        if (t < 21) GATE4;
        else if (t == 21) GATE0;
        if (t < 23) BAR;
    }

    // ---- epilogue: per-row argmin -> packed u64 (monotonic dist, global k)
    __syncthreads();
    unsigned long long* kbuf = (unsigned long long*)lds;  // [256][4]
    float wv[4];
#pragma unroll
    for (int nf = 0; nf < 4; ++nf) wv[nf] = ww[nt * 256 + wn * 64 + nf * 16 + col];
#pragma unroll
    for (int mf = 0; mf < 8; ++mf)
#pragma unroll
        for (int r = 0; r < 4; ++r) {
            unsigned long long key = ~0ull;
#pragma unroll
            for (int nf = 0; nf < 4; ++nf) {
                int kg = nt * 256 + wn * 64 + nf * 16 + col;
                float sd = wv[nf] - 2.f * acc[mf][nf][r];
                unsigned u = __float_as_uint(sd);
                u = (u & 0x80000000u) ? ~u : (u | 0x80000000u);
                unsigned long long kk = ((unsigned long long)u << 32) | (unsigned)kg;
                key = kk < key ? kk : key;
            }
#pragma unroll
            for (int off = 1; off < 16; off <<= 1) {
                unsigned klo = __shfl_xor((unsigned)key, off, 64);
                unsigned khi = __shfl_xor((unsigned)(key >> 32), off, 64);
                unsigned long long ok = ((unsigned long long)khi << 32) | klo;
                key = ok < key ? ok : key;
            }
            if (col == 0) kbuf[(wm * 128 + mf * 16 + q * 4 + r) * 4 + wn] = key;
        }
    __syncthreads();
    if (tid < 256) {
        unsigned long long k0 = kbuf[tid * 4], k1 = kbuf[tid * 4 + 1];
        unsigned long long k2 = kbuf[tid * 4 + 2], k3 = kbuf[tid * 4 + 3];
        unsigned long long km = k0 < k1 ? k0 : k1;
        km = k2 < km ? k2 : km;
        km = k3 < km ? k3 : km;
        pbest[(size_t)nt * 65536 + mb * 256 + tid] = km;
    }
#undef GATE4
#undef GATE0
#undef BAR
}

// --------------------- gather: cross-block argmin + idx + z_out + loss + counts
__global__ __launch_bounds__(256) void gather_kernel(
        const float* __restrict__ in, const float* __restrict__ cb,
        const unsigned long long* __restrict__ pbest, float* __restrict__ idx_out,
        unsigned int* __restrict__ counts, float* __restrict__ zout,
        float* __restrict__ partials) {
    const int tid = threadIdx.x;
    const int n   = blockIdx.x * 256 + tid;
    unsigned long long km = pbest[n];
#pragma unroll
    for (int nt = 1; nt < 4; ++nt) {
        unsigned long long k = pbest[(size_t)nt * 65536 + n];
        km = k < km ? k : km;
    }
    const int r = (int)(km & 0xFFFFFFFFu);
    idx_out[n] = (float)r;
    atomicAdd(&counts[r], 1u);

    const int b = n >> 12, hw = n & 4095;
    const float* row = cb + (size_t)r * DDIM;
    const float* xp  = in   + (size_t)b * CHW + hw;
    float*       zp  = zout + (size_t)b * CHW + hw;
    float sum = 0.f;
#pragma unroll 4
    for (int c = 0; c < DDIM; ++c) {
        float v = row[c];
        float x = xp[(size_t)c * HWSZ];
        zp[(size_t)c * HWSZ] = v;
        float d = v - x;
        sum += d * d;
    }
#pragma unroll
    for (int o = 32; o; o >>= 1) sum += __shfl_down(sum, o, 64);
    __shared__ float ps[4];
    if ((tid & 63) == 0) ps[tid >> 6] = sum;
    __syncthreads();
    if (tid == 0) partials[blockIdx.x] = ps[0] + ps[1] + ps[2] + ps[3];
}

// ------------------------------------------------------- loss + perplexity
__global__ __launch_bounds__(256) void final_kernel(
        const float* __restrict__ partials, const unsigned int* __restrict__ counts,
        float* __restrict__ out_loss, float* __restrict__ out_perp) {
    const int tid = threadIdx.x;
    float s = partials[tid];
    float e = 0.f;
#pragma unroll
    for (int qq = 0; qq < 4; ++qq) {
        float p = (float)counts[tid * 4 + qq] * (1.f / 65536.f);
        e += p * logf(p + 1e-10f);
    }
#pragma unroll
    for (int o = 32; o; o >>= 1) {
        s += __shfl_down(s, o, 64);
        e += __shfl_down(e, o, 64);
    }
    __shared__ float ss[4], es[4];
    if ((tid & 63) == 0) { ss[tid >> 6] = s; es[tid >> 6] = e; }
    __syncthreads();
    if (tid == 0) {
        float S = ss[0] + ss[1] + ss[2] + ss[3];
        float E = es[0] + es[1] + es[2] + es[3];
        *out_loss = 0.25f * (S / (float)ZELEMS);
        *out_perp = expf(-E);
    }
}

extern "C" void kernel_launch(void* const* d_in, const int* in_sizes, int n_in,
                              void* d_out, int out_size, void* d_ws, size_t ws_size,
                              hipStream_t stream) {
    (void)in_sizes; (void)n_in; (void)out_size; (void)ws_size;
    const float* in = (const float*)d_in[0];
    const float* cb = (const float*)d_in[1];
    float* out  = (float*)d_out;
    float* zout = out;
    float* loss = out + ZELEMS;
    float* perp = out + ZELEMS + 1;
    float* idxf = out + ZELEMS + 2;

    unsigned int*       counts   = (unsigned int*)d_ws;
    float*              ww       = (float*)((char*)d_ws + 4096);
    float*              partials = (float*)((char*)d_ws + 8192);
    unsigned short*     Ws       = (unsigned short*)((char*)d_ws + 16384);
    unsigned long long* pbest    = (unsigned long long*)((char*)d_ws + 1064960);
    unsigned short*     Xs       = (unsigned short*)zout;  // scratch; overwritten later

    hipMemsetAsync(counts, 0, 4096, stream);
    conv_w      <<<32,   256, 0, stream>>>(cb, Ws, ww);
    conv_x      <<<4096, 256, 0, stream>>>(in, Xs);
    gemm_argmin <<<1024, 512, 0, stream>>>(Xs, Ws, ww, pbest);
    gather_kernel<<<256, 256, 0, stream>>>(in, cb, pbest, idxf, counts, zout, partials);
    final_kernel <<<1,   256, 0, stream>>>(partials, counts, loss, perp);
}

// Round 9
// 210.487 us; speedup vs baseline: 1.1940x; 1.1940x over previous
//
#include <hip/hip_runtime.h>
#include <math.h>

// VQ-VAE forward. inputs [16,256,64,64] f32 NCHW, codebook [1024,256] f32.
// N = 65536 points, D = 256, K = 1024.
// d_out f32: z_out [16,256,64,64] | loss | perplexity | idx [65536,1]
#define NPTS   65536
#define DDIM   256
#define KCODES 1024
#define HWSZ   4096
#define ZELEMS 16777216
#define CHW    1048576

// bf16-split GEMM, 3-product contraction 768 = [xhi|xhi|xlo].[whi|wlo|whi].
// m201-style 8-phase schedule: BK=64 (2 chunks/iter), 12 iters, 2 LDS bufs
// x 64 KB, 4 quadrant-phases/iter {reads; bar; 16 MFMA; bar}, stage distance
// 2 iters into dead regions of the current buffer, one vmcnt(8) gate/iter.
// X layout: [mt 256][chunk 16][rh 2][ms 8][lane 64][8] bf16 (64 MiB, z_out scratch)
// W layout: [ct 4][chunk 16][ch 2][ms 8][lane 64][8] bf16 (1 MiB, ws)
// ws: counts u32[1K] @0 | ww f32[1K] @4096 | partials @8192 | Ws @16384 | pbest u64[4][64K] @1064960

typedef __attribute__((ext_vector_type(8))) short s16x8;
typedef __attribute__((ext_vector_type(4))) float f32x4;

#define AS1 __attribute__((address_space(1)))
#define AS3 __attribute__((address_space(3)))

__device__ __forceinline__ void bf16split(float x, unsigned short& h, unsigned short& l) {
    unsigned u  = __float_as_uint(x);
    unsigned hu = (u + 0x8000u) & 0xFFFF0000u;
    h = (unsigned short)(hu >> 16);
    float r = x - __uint_as_float(hu);
    l = (unsigned short)((__float_as_uint(r) + 0x8000u) >> 16);
}

// ------------------------------------------- conv_w: codebook -> tiles + ||w||^2
__global__ __launch_bounds__(256) void conv_w(const float* __restrict__ cb,
                                              unsigned short* __restrict__ Ws,
                                              float* __restrict__ ww) {
    int gid  = blockIdx.x * 256 + threadIdx.x;           // 0..8191
    int code = gid >> 3, o32 = gid & 7;
    int ct = code >> 8, r256 = code & 255, rh = r256 >> 7, rr = r256 & 127;
    unsigned short hi[32], lo[32];
    float ss = 0.f;
#pragma unroll
    for (int j4 = 0; j4 < 8; ++j4) {
        float4 v = *(const float4*)(cb + (size_t)code * DDIM + o32 * 32 + j4 * 4);
        ss += v.x * v.x + v.y * v.y + v.z * v.z + v.w * v.w;
        bf16split(v.x, hi[j4*4+0], lo[j4*4+0]);
        bf16split(v.y, hi[j4*4+1], lo[j4*4+1]);
        bf16split(v.z, hi[j4*4+2], lo[j4*4+2]);
        bf16split(v.w, hi[j4*4+3], lo[j4*4+3]);
    }
    ss += __shfl_down(ss, 4, 8);
    ss += __shfl_down(ss, 2, 8);
    ss += __shfl_down(ss, 1, 8);
    if (o32 == 0) ww[code] = ss;
    size_t bh = (size_t)ct * 131072 + (size_t)o32       * 8192 + rh * 4096 + (rr >> 4) * 512;
    size_t bl = (size_t)ct * 131072 + (size_t)(o32 + 8) * 8192 + rh * 4096 + (rr >> 4) * 512;
#pragma unroll
    for (int oct = 0; oct < 4; ++oct) {
        size_t fo = (size_t)((rr & 15) + 16 * oct) * 8;
        *(s16x8*)(Ws + bh + fo) = *(const s16x8*)&hi[oct * 8];
        *(s16x8*)(Ws + bl + fo) = *(const s16x8*)&lo[oct * 8];
    }
}

// --------------------------------- conv_x: NCHW f32 -> fragment-ordered bf16
__global__ __launch_bounds__(256) void conv_x(const float* __restrict__ in,
                                              unsigned short* __restrict__ Xs) {
    __shared__ float xt[32 * 128];                       // 16 KB
    const int tid = threadIdx.x;
    const int rg = blockIdx.x >> 3, dc = blockIdx.x & 7;
    const int mt = rg >> 1, rhalf = rg & 1;
    const int b = (rg * 128) >> 12, hw0 = (rg * 128) & 4095;
    const float* src = in + (size_t)b * CHW + (size_t)(dc * 32) * HWSZ + hw0;
#pragma unroll
    for (int r = 0; r < 16; ++r) {
        int e = r * 256 + tid, dd = e >> 7, i = e & 127;
        xt[dd * 128 + i] = src[(size_t)dd * HWSZ + i];
    }
    __syncthreads();
#pragma unroll
    for (int hl = 0; hl < 2; ++hl) {
        int g = hl * 256 + tid;
        int row = g >> 2, o = g & 3;
        unsigned short hi[8], lo[8];
#pragma unroll
        for (int j = 0; j < 8; ++j)
            bf16split(xt[(o * 8 + j) * 128 + row], hi[j], lo[j]);
        size_t fo = rhalf * 4096 + (size_t)(row >> 4) * 512 + (size_t)((row & 15) + 16 * o) * 8;
        size_t bh = (size_t)mt * 131072 + (size_t)dc       * 8192 + fo;
        size_t bl = (size_t)mt * 131072 + (size_t)(dc + 8) * 8192 + fo;
        *(s16x8*)(Xs + bh) = *(const s16x8*)hi;
        *(s16x8*)(Xs + bl) = *(const s16x8*)lo;
    }
}

// --------------------------------------- gemm_argmin: 8-phase MFMA + argmin
// 1024 blocks x 512 threads (8 waves 2Mx4N; wave tile 128x64). BK=64, 12 iters.
// XCD swizzle: 4 nt-blocks of one mb run concurrently on one XCD (share X in L2).
__global__ __launch_bounds__(512) void gemm_argmin(
        const unsigned short* __restrict__ Xs, const unsigned short* __restrict__ Ws,
        const float* __restrict__ ww, unsigned long long* __restrict__ pbest) {
    __shared__ unsigned short lds[65536];                // 128 KB = 2 bufs x 32768 shorts
    const int tid = threadIdx.x, lane = tid & 63, w = tid >> 6;
    const int wm = w >> 2, wn = w & 3;
    const int col = lane & 15, q = lane >> 4;
    const int bid = blockIdx.x;
    const int xcd = bid & 7, slot = bid >> 3;
    const int nt = slot & 3, mb = (slot >> 2) * 8 + xcd;

    const unsigned short* XsB = Xs + (size_t)mb * 131072;
    const unsigned short* WsB = Ws + (size_t)nt * 131072;

    f32x4 acc[8][4] = {};

    const int aBase = wm * 4096 + lane * 8;              // within [kc] section
    const int bBase = 16384 + (wn >> 1) * 4096 + (wn & 1) * 2048 + lane * 8;

    auto SA = [&](int g, int rh, int p) {                // stage A granule (8 KB)
        const int kA = (g & 7) | ((g >> 4) << 3);        // xhi,xhi,xlo
        const unsigned short* src = XsB + kA * 8192 + rh * 4096 + tid * 8;
        __builtin_amdgcn_global_load_lds(
            (const AS1 unsigned*)src,
            (AS3 unsigned*)&lds[p * 32768 + (g & 1) * 8192 + rh * 4096 + w * 512], 16, 0, 0);
    };
    auto SB = [&](int g, int ch, int p) {                // stage B granule (8 KB)
        const int kW = (g & 7) | (((g >> 3) & 1) << 3);  // whi,wlo,whi
        const unsigned short* src = WsB + kW * 8192 + ch * 4096 + tid * 8;
        __builtin_amdgcn_global_load_lds(
            (const AS1 unsigned*)src,
            (AS3 unsigned*)&lds[p * 32768 + 16384 + (g & 1) * 8192 + ch * 4096 + w * 512], 16, 0, 0);
    };
#define GATE8 asm volatile("s_waitcnt vmcnt(8)" ::: "memory")
#define GATE0 asm volatile("s_waitcnt vmcnt(0)" ::: "memory")
#define BAR   do { __builtin_amdgcn_s_barrier(); __builtin_amdgcn_sched_barrier(0); } while (0)

    // iter: 4 phases {reads; BAR; 16 MFMA quadrant; BAR}; stage tau+2 at ph3/ph4.
    auto ITER = [&](int tau, const int p, bool stg, int gate) {
        const int bb = p * 32768;
        s16x8 aL[2][4], aH[2][4], bL[2][2], bH[2][2];
        // ---- ph1: reads B(nf0,1) + A(mf0-3), both kc
#pragma unroll
        for (int kc = 0; kc < 2; ++kc) {
            bL[kc][0] = *(const s16x8*)&lds[bb + kc * 8192 + bBase];
            bL[kc][1] = *(const s16x8*)&lds[bb + kc * 8192 + bBase + 512];
#pragma unroll
            for (int mf = 0; mf < 4; ++mf)
                aL[kc][mf] = *(const s16x8*)&lds[bb + kc * 8192 + aBase + mf * 512];
        }
        BAR;
        __builtin_amdgcn_s_setprio(1);
#pragma unroll
        for (int kc = 0; kc < 2; ++kc)
#pragma unroll
            for (int mf = 0; mf < 4; ++mf)
#pragma unroll
                for (int nf = 0; nf < 2; ++nf)
                    acc[mf][nf] = __builtin_amdgcn_mfma_f32_16x16x32_bf16(
                        aL[kc][mf], bL[kc][nf], acc[mf][nf], 0, 0, 0);
        __builtin_amdgcn_s_setprio(0);
        BAR;
        // ---- ph2: reads B(nf2,3)
#pragma unroll
        for (int kc = 0; kc < 2; ++kc) {
            bH[kc][0] = *(const s16x8*)&lds[bb + kc * 8192 + bBase + 1024];
            bH[kc][1] = *(const s16x8*)&lds[bb + kc * 8192 + bBase + 1536];
        }
        BAR;
        __builtin_amdgcn_s_setprio(1);
#pragma unroll
        for (int kc = 0; kc < 2; ++kc)
#pragma unroll
            for (int mf = 0; mf < 4; ++mf)
#pragma unroll
                for (int nf = 0; nf < 2; ++nf)
                    acc[mf][nf + 2] = __builtin_amdgcn_mfma_f32_16x16x32_bf16(
                        aL[kc][mf], bH[kc][nf], acc[mf][nf + 2], 0, 0, 0);
        __builtin_amdgcn_s_setprio(0);
        BAR;
        // ---- ph3: reads A(mf4-7); stage tau+2's B (region dead since ph2 BAR)
#pragma unroll
        for (int kc = 0; kc < 2; ++kc)
#pragma unroll
            for (int mf = 0; mf < 4; ++mf)
                aH[kc][mf] = *(const s16x8*)&lds[bb + kc * 8192 + aBase + (4 + mf) * 512];
        if (stg) {
            SB(2 * tau + 4, 0, p); SB(2 * tau + 5, 0, p);
            SB(2 * tau + 4, 1, p); SB(2 * tau + 5, 1, p);
        }
        BAR;
        __builtin_amdgcn_s_setprio(1);
#pragma unroll
        for (int kc = 0; kc < 2; ++kc)
#pragma unroll
            for (int mf = 0; mf < 4; ++mf)
#pragma unroll
                for (int nf = 0; nf < 2; ++nf)
                    acc[mf + 4][nf] = __builtin_amdgcn_mfma_f32_16x16x32_bf16(
                        aH[kc][mf], bL[kc][nf], acc[mf + 4][nf], 0, 0, 0);
        __builtin_amdgcn_s_setprio(0);
        BAR;
        // ---- ph4: no reads; stage tau+2's A (region dead since ph3 BAR); gate
        if (stg) {
            SA(2 * tau + 4, 0, p); SA(2 * tau + 5, 0, p);
            SA(2 * tau + 4, 1, p); SA(2 * tau + 5, 1, p);
        }
        if (gate == 8)      GATE8;
        else if (gate == 0) GATE0;
        __builtin_amdgcn_sched_barrier(0);
        __builtin_amdgcn_s_setprio(1);
#pragma unroll
        for (int kc = 0; kc < 2; ++kc)
#pragma unroll
            for (int mf = 0; mf < 4; ++mf)
#pragma unroll
                for (int nf = 0; nf < 2; ++nf)
                    acc[mf + 4][nf + 2] = __builtin_amdgcn_mfma_f32_16x16x32_bf16(
                        aH[kc][mf], bH[kc][nf], acc[mf + 4][nf + 2], 0, 0, 0);
        __builtin_amdgcn_s_setprio(0);
        BAR;
    };

    // prologue: stage K-tiles 0 (buf0) and 1 (buf1); drain K0; enter loop
#pragma unroll
    for (int g = 0; g < 4; ++g) {
        const int p = g >> 1;
        SA(g, 0, p); SA(g, 1, p); SB(g, 0, p); SB(g, 1, p);
    }
    GATE8;
    BAR;

    for (int tq = 0; tq < 5; ++tq) {                     // tau = 0..9
        ITER(2 * tq,     0, true, 8);
        ITER(2 * tq + 1, 1, true, 8);
    }
    ITER(10, 0, false, 0);
    ITER(11, 1, false, -1);

    // ---- epilogue: per-row argmin -> packed u64 (monotonic dist, global k)
    __syncthreads();
    unsigned long long* kbuf = (unsigned long long*)lds;  // [256][4]
    float wv[4];
#pragma unroll
    for (int nf = 0; nf < 4; ++nf) wv[nf] = ww[nt * 256 + wn * 64 + nf * 16 + col];
#pragma unroll
    for (int mf = 0; mf < 8; ++mf)
#pragma unroll
        for (int r = 0; r < 4; ++r) {
            unsigned long long key = ~0ull;
#pragma unroll
            for (int nf = 0; nf < 4; ++nf) {
                int kg = nt * 256 + wn * 64 + nf * 16 + col;
                float sd = wv[nf] - 2.f * acc[mf][nf][r];
                unsigned u = __float_as_uint(sd);
                u = (u & 0x80000000u) ? ~u : (u | 0x80000000u);
                unsigned long long kk = ((unsigned long long)u << 32) | (unsigned)kg;
                key = kk < key ? kk : key;
            }
#pragma unroll
            for (int off = 1; off < 16; off <<= 1) {
                unsigned klo = __shfl_xor((unsigned)key, off, 64);
                unsigned khi = __shfl_xor((unsigned)(key >> 32), off, 64);
                unsigned long long ok = ((unsigned long long)khi << 32) | klo;
                key = ok < key ? ok : key;
            }
            if (col == 0) kbuf[(wm * 128 + mf * 16 + q * 4 + r) * 4 + wn] = key;
        }
    __syncthreads();
    if (tid < 256) {
        unsigned long long k0 = kbuf[tid * 4], k1 = kbuf[tid * 4 + 1];
        unsigned long long k2 = kbuf[tid * 4 + 2], k3 = kbuf[tid * 4 + 3];
        unsigned long long km = k0 < k1 ? k0 : k1;
        km = k2 < km ? k2 : km;
        km = k3 < km ? k3 : km;
        pbest[(size_t)nt * 65536 + mb * 256 + tid] = km;
    }
#undef GATE8
#undef GATE0
#undef BAR
}

// --------------------- gather: cross-block argmin + idx + z_out + loss + counts
__global__ __launch_bounds__(256) void gather_kernel(
        const float* __restrict__ in, const float* __restrict__ cb,
        const unsigned long long* __restrict__ pbest, float* __restrict__ idx_out,
        unsigned int* __restrict__ counts, float* __restrict__ zout,
        float* __restrict__ partials) {
    const int tid = threadIdx.x;
    const int n   = blockIdx.x * 256 + tid;
    unsigned long long km = pbest[n];
#pragma unroll
    for (int nt = 1; nt < 4; ++nt) {
        unsigned long long k = pbest[(size_t)nt * 65536 + n];
        km = k < km ? k : km;
    }
    const int r = (int)(km & 0xFFFFFFFFu);
    idx_out[n] = (float)r;
    atomicAdd(&counts[r], 1u);

    const int b = n >> 12, hw = n & 4095;
    const float* row = cb + (size_t)r * DDIM;
    const float* xp  = in   + (size_t)b * CHW + hw;
    float*       zp  = zout + (size_t)b * CHW + hw;
    float sum = 0.f;
#pragma unroll 4
    for (int c = 0; c < DDIM; ++c) {
        float v = row[c];
        float x = xp[(size_t)c * HWSZ];
        zp[(size_t)c * HWSZ] = v;
        float d = v - x;
        sum += d * d;
    }
#pragma unroll
    for (int o = 32; o; o >>= 1) sum += __shfl_down(sum, o, 64);
    __shared__ float ps[4];
    if ((tid & 63) == 0) ps[tid >> 6] = sum;
    __syncthreads();
    if (tid == 0) partials[blockIdx.x] = ps[0] + ps[1] + ps[2] + ps[3];
}

// ------------------------------------------------------- loss + perplexity
__global__ __launch_bounds__(256) void final_kernel(
        const float* __restrict__ partials, const unsigned int* __restrict__ counts,
        float* __restrict__ out_loss, float* __restrict__ out_perp) {
    const int tid = threadIdx.x;
    float s = partials[tid];
    float e = 0.f;
#pragma unroll
    for (int qq = 0; qq < 4; ++qq) {
        float p = (float)counts[tid * 4 + qq] * (1.f / 65536.f);
        e += p * logf(p + 1e-10f);
    }
#pragma unroll
    for (int o = 32; o; o >>= 1) {
        s += __shfl_down(s, o, 64);
        e += __shfl_down(e, o, 64);
    }
    __shared__ float ss[4], es[4];
    if ((tid & 63) == 0) { ss[tid >> 6] = s; es[tid >> 6] = e; }
    __syncthreads();
    if (tid == 0) {
        float S = ss[0] + ss[1] + ss[2] + ss[3];
        float E = es[0] + es[1] + es[2] + es[3];
        *out_loss = 0.25f * (S / (float)ZELEMS);
        *out_perp = expf(-E);
    }
}

extern "C" void kernel_launch(void* const* d_in, const int* in_sizes, int n_in,
                              void* d_out, int out_size, void* d_ws, size_t ws_size,
                              hipStream_t stream) {
    (void)in_sizes; (void)n_in; (void)out_size; (void)ws_size;
    const float* in = (const float*)d_in[0];
    const float* cb = (const float*)d_in[1];
    float* out  = (float*)d_out;
    float* zout = out;
    float* loss = out + ZELEMS;
    float* perp = out + ZELEMS + 1;
    float* idxf = out + ZELEMS + 2;

    unsigned int*       counts   = (unsigned int*)d_ws;
    float*              ww       = (float*)((char*)d_ws + 4096);
    float*              partials = (float*)((char*)d_ws + 8192);
    unsigned short*     Ws       = (unsigned short*)((char*)d_ws + 16384);
    unsigned long long* pbest    = (unsigned long long*)((char*)d_ws + 1064960);
    unsigned short*     Xs       = (unsigned short*)zout;  // scratch; overwritten later

    hipMemsetAsync(counts, 0, 4096, stream);
    conv_w      <<<32,   256, 0, stream>>>(cb, Ws, ww);
    conv_x      <<<4096, 256, 0, stream>>>(in, Xs);
    gemm_argmin <<<1024, 512, 0, stream>>>(Xs, Ws, ww, pbest);
    gather_kernel<<<256, 256, 0, stream>>>(in, cb, pbest, idxf, counts, zout, partials);
    final_kernel <<<1,   256, 0, stream>>>(partials, counts, loss, perp);
}